// Round 4
// baseline (1023.641 us; speedup 1.0000x reference)
//
#include <hip/hip_runtime.h>
#include <hip/hip_bf16.h>
#include <stdint.h>
#include <string.h>

// Problem constants
#define S_LEN 512
#define NBATCH 64
#define EDIM 128
#define HDIM 256
#define GDIM 1024  // 4*H

typedef __attribute__((ext_vector_type(8))) short short8;   // 8 bf16 (4 VGPRs) MFMA frag
typedef __attribute__((ext_vector_type(4))) short short4v;  // 4 bf16
typedef __attribute__((ext_vector_type(4))) float float4v;  // MFMA acc

// Workspace layout (bytes)
#define OFF_WHH8 0u
#define SZ_WHH8 (64u * 8u * 64u * 8u)        // 256 KB: W_hh_f fp8 A-frags
#define OFF_WIH (OFF_WHH8 + SZ_WHH8)
#define SZ_WIH (64u * 4u * 64u * 16u)        // 256 KB: W_ih_f bf16 frags
#define OFF_XG ((size_t)(OFF_WIH + SZ_WIH))
#define SZ_XG ((size_t)S_LEN * NBATCH * GDIM * 2)  // 67 MB: xg bf16 [t][b][1024]
#define OFF_HF (OFF_XG + SZ_XG)              // 64 KB: h_f final, fp32 [64][256]

__device__ __forceinline__ short f2bf(float f) {
    union { float f; unsigned u; } v;
    v.f = f;
    unsigned r = (v.u + 0x7fffu + ((v.u >> 16) & 1u)) >> 16;  // RNE
    return (short)r;
}
__device__ __forceinline__ float bf2f(short s) {
    union { unsigned u; float f; } v;
    v.u = ((unsigned)(unsigned short)s) << 16;
    return v.f;
}
__device__ __forceinline__ float sigm(float x) {
    float e = __expf(-x);                    // v_exp
    return __builtin_amdgcn_rcpf(1.0f + e);  // v_rcp
}
__device__ __forceinline__ float tanh_(float x) {
    float e = __expf(2.0f * x);              // overflow -> inf -> rcp 0 -> +1; underflow -> -1
    return 1.0f - 2.0f * __builtin_amdgcn_rcpf(e + 1.0f);
}

// ---------------------------------------------------------------------------
// Prep A: fp32 W_ih [G,128] -> bf16 MFMA A-fragments (lane(ln,q) holds
// W[tile*16+ln][c*32+q*8+j], j=0..7).
// ---------------------------------------------------------------------------
__global__ __launch_bounds__(256) void prep_frags(const float* __restrict__ src,
                                                  char* __restrict__ dst,
                                                  int K, int nchunks, int nfrags) {
    int id = blockIdx.x * blockDim.x + threadIdx.x;
    int lane = id & 63;
    int f = id >> 6;
    if (f >= nfrags) return;
    int tile = f / nchunks;
    int c = f - tile * nchunks;
    int row = tile * 16 + (lane & 15);
    int k0 = c * 32 + ((lane >> 4) * 8);
    const float* s = src + (size_t)row * K + k0;
    short8 pack;
#pragma unroll
    for (int j = 0; j < 8; ++j) pack[j] = f2bf(s[j]);
    *(short8*)(dst + ((size_t)f * 64 + lane) * 16) = pack;
}

// ---------------------------------------------------------------------------
// Prep B: fp32 W_hh [1024,256] -> fp8 e4m3 A-fragments for mfma 16x16x32_fp8.
// Fragment f = tile*8 + c; lane(ln,q) holds 8 fp8 bytes
// W[tile*16+ln][c*32+q*8+j], j=0..7.
// ---------------------------------------------------------------------------
__global__ __launch_bounds__(256) void prep_whh_fp8(const float* __restrict__ src,
                                                    char* __restrict__ dst) {
    int id = blockIdx.x * blockDim.x + threadIdx.x;
    int lane = id & 63;
    int f = id >> 6;  // tile*8 + c, f < 512
    int tile = f >> 3, c = f & 7;
    int row = tile * 16 + (lane & 15);
    int k0 = c * 32 + ((lane >> 4) * 8);
    const float* s = src + (size_t)row * HDIM + k0;
    int d0 = __builtin_amdgcn_cvt_pk_fp8_f32(s[0], s[1], 0, false);
    d0 = __builtin_amdgcn_cvt_pk_fp8_f32(s[2], s[3], d0, true);
    int d1 = __builtin_amdgcn_cvt_pk_fp8_f32(s[4], s[5], 0, false);
    d1 = __builtin_amdgcn_cvt_pk_fp8_f32(s[6], s[7], d1, true);
    int* o = (int*)(dst + ((size_t)f * 64 + lane) * 8);
    o[0] = d0;
    o[1] = d1;
}

// ---------------------------------------------------------------------------
// Input projection (transposed): xg[t][b][j] = x[t,b,:] @ W_ih^T + b_f (bf16).
// A = W_ih frag, B = x^T frag -> C[m=j][n=batch].
// ---------------------------------------------------------------------------
__global__ __launch_bounds__(256) void input_proj(const int* __restrict__ seq,
                                                  const float* __restrict__ emb,
                                                  const char* __restrict__ wih_frags,
                                                  const float* __restrict__ bias,
                                                  char* __restrict__ xg) {
    __shared__ __align__(16) short lx[4][16][136];  // bf16 x-tiles, +8 pad
    int tid = threadIdx.x;
    int t0 = blockIdx.x * 4;
    int g = blockIdx.y;

    // stage x: 64 rows (4 t x 16 batch), 4 threads/row, 32 elems each
    {
        int row = tid >> 2;
        int tt = row >> 4, m = row & 15;
        int k0 = (tid & 3) * 32;
        int v = seq[(t0 + tt) * NBATCH + g * 16 + m];
        const float* src = emb + (size_t)v * EDIM + k0;
        bool zero = (v == 0);
#pragma unroll
        for (int u = 0; u < 32; u += 4) {
            float4v f = *(const float4v*)(src + u);
            short4v p;
#pragma unroll
            for (int e = 0; e < 4; ++e) p[e] = zero ? (short)0 : f2bf(f[e]);
            *(short4v*)&lx[tt][m][k0 + u] = p;
        }
    }
    __syncthreads();

    int lane = tid & 63, w = tid >> 6;
    int ln = lane & 15, q = lane >> 4;

    short8 Bx[4][4];  // x^T B-frags [t][kchunk]
#pragma unroll
    for (int tt = 0; tt < 4; ++tt)
#pragma unroll
        for (int c = 0; c < 4; ++c)
            Bx[tt][c] = *(const short8*)&lx[tt][ln][c * 32 + q * 8];

    for (int nt = 0; nt < 16; ++nt) {
        int tile = w * 16 + nt;
        short8 Aw[4];
#pragma unroll
        for (int c = 0; c < 4; ++c)
            Aw[c] = *(const short8*)(wih_frags + (((size_t)tile * 4 + c) * 64 + lane) * 16);
        float4v b4 = *(const float4v*)(bias + tile * 16 + q * 4);
#pragma unroll
        for (int tt = 0; tt < 4; ++tt) {
            float4v acc = b4;
#pragma unroll
            for (int c = 0; c < 4; ++c)
                acc = __builtin_amdgcn_mfma_f32_16x16x32_bf16(Aw[c], Bx[tt][c], acc, 0, 0, 0);
            short4v p;
#pragma unroll
            for (int r = 0; r < 4; ++r) p[r] = f2bf(acc[r]);
            size_t off = ((size_t)(t0 + tt) * NBATCH + g * 16 + ln) * GDIM + tile * 16 + q * 4;
            *(short4v*)(xg + off * 2) = p;
        }
    }
}

// ---------------------------------------------------------------------------
// Forward LSTM scan, v4 (fp8, 16 blocks x 4 batches, lane-dense activations).
//   Grid = 16 blocks, 1024 threads = 16 waves. Same register-resident fp8
//   W_hh GEMM as v3 (C[m=j][n=batch], batch cols 0..3 valid; h rows 4..15
//   stay zero so garbage cols are finite and ignored). After the MFMA, a
//   SAME-WAVE LDS scratch round-trip redistributes the 16 valid gate values
//   per source lane so every lane owns one (batch,j) element: 5 trans pairs
//   per lane (was 20) -> trans-pipe work per CU drops 4x vs v3, and it now
//   runs on 16 CUs instead of 4. One __syncthreads per step (h dbuf).
// ---------------------------------------------------------------------------
__global__ __launch_bounds__(1024, 4) void lstm_scan(const char* __restrict__ whh8,
                                                     const char* __restrict__ xg,
                                                     float* __restrict__ hf_out) {
    __shared__ __align__(16) char hls[2][16][272];     // h fp8 [buf][batch][H], +16 pad
    __shared__ __align__(16) float scr[16][16 * 20];   // per-wave: 16 src x (4 gate x 4 r), +4 pad
    int tid = threadIdx.x;
    int lane = tid & 63, w = tid >> 6;     // w = 0..15: hidden j-tile
    int ln = lane & 15, q = lane >> 4;
    int bg = blockIdx.x;                    // 16 batch groups of 4

    // W_hh fp8 A-frags -> registers (gate tiles i,f,g,o at j-tile w): 64 regs
    long long Wfr[4][8];
#pragma unroll
    for (int blk = 0; blk < 4; ++blk) {
        int tile = 16 * blk + w;
#pragma unroll
        for (int c = 0; c < 8; ++c)
            Wfr[blk][c] = *(const long long*)(whh8 + (((size_t)tile * 8 + c) * 64 + lane) * 8);
    }

    // zero both h buffers (rows 4..15 stay zero forever -> garbage cols finite)
    {
        int* hp = (int*)&hls[0][0][0];
        for (int i = tid; i < (2 * 16 * 272) / 4; i += 1024) hp[i] = 0;
    }

    const char* hrd = &hls[0][0][0];
    char* hwr = &hls[1][0][0];
    int hoff_rd = ln * 272 + q * 8;          // + c*32 per chunk (B-frag read)

    // element-phase ownership: lane (q, rr, b) owns (batch b, j = w*16+q*4+rr)
    int b = ln & 3;
    int rr = ln >> 2;
    int j = w * 16 + q * 4 + rr;
    int hoff_wr = b * 272 + j;               // 1 fp8 byte
    float* swr = &scr[w][0] + (q * 4 + ln) * 20;       // source write (valid ln<4)
    const float* srd = &scr[w][0] + (q * 4 + b) * 20 + rr;  // gather: +gate*4

    float cst = 0.0f;

    // xg: batch for MFMA col = bg*4 + (ln&3); gate offset blk*512 bytes
    const char* xgp = xg + (((size_t)(bg * 4 + b) * GDIM + w * 16 + q * 4) * 2);
    const size_t tstep = (size_t)NBATCH * GDIM * 2;  // 131072 B

    short4v xv[4];
#pragma unroll
    for (int blk = 0; blk < 4; ++blk)
        xv[blk] = *(const short4v*)(xgp + blk * 512);

    __syncthreads();

    for (int t = 0; t < S_LEN; ++t) {
        // h(t-1) B-frags from read buffer
        long long Bh[8];
#pragma unroll
        for (int c = 0; c < 8; ++c)
            Bh[c] = *(const long long*)(hrd + hoff_rd + c * 32);

        // acc init from prefetched xg
        float4v a[4];
#pragma unroll
        for (int blk = 0; blk < 4; ++blk)
#pragma unroll
            for (int r = 0; r < 4; ++r) a[blk][r] = bf2f(xv[blk][r]);

        // prefetch next step's xg (in flight across the whole step)
        xgp += tstep;
        if (t != S_LEN - 1) {
#pragma unroll
            for (int blk = 0; blk < 4; ++blk)
                xv[blk] = *(const short4v*)(xgp + blk * 512);
        }

        // 4 independent MFMA chains, chunk-major
#pragma unroll
        for (int c = 0; c < 8; ++c)
#pragma unroll
            for (int blk = 0; blk < 4; ++blk)
                a[blk] = __builtin_amdgcn_mfma_f32_16x16x32_fp8_fp8(Wfr[blk][c], Bh[c], a[blk], 0, 0, 0);

        // same-wave scratch redistribution: source lanes (ln<4) publish 16 gates
        if (ln < 4) {
#pragma unroll
            for (int blk = 0; blk < 4; ++blk)
                *(float4v*)(swr + blk * 4) = a[blk];
        }
        // gather one element's i,f,g,o (same wave; compiler inserts lgkmcnt wait)
        float gi = srd[0];
        float gf = srd[4];
        float gg = srd[8];
        float go = srd[12];

        // activations + cell update (one element per lane)
        float iv = sigm(gi);
        float fv = sigm(gf);
        float gv = tanh_(gg);
        float ov = sigm(go);
        float cv = fv * cst + iv * gv;
        cst = cv;
        float hv = ov * tanh_(cv);

        // h -> fp8 byte into other buffer
        int pk = __builtin_amdgcn_cvt_pk_fp8_f32(hv, hv, 0, false);
        hwr[hoff_wr] = (char)pk;

        if (t == S_LEN - 1)
            hf_out[((size_t)(bg * 4 + b)) * HDIM + j] = hv;

        const char* tr = hrd; hrd = hwr; hwr = (char*)tr;
        __syncthreads();
    }
}

// ---------------------------------------------------------------------------
// Tail: backward cell at position S-1 (h0=c0=0 => W_hh_b unused) + output proj.
// One block per batch element; thread j handles hidden unit j.
// ---------------------------------------------------------------------------
__global__ __launch_bounds__(256) void tail_kernel(const int* __restrict__ seq,
                                                   const float* __restrict__ emb,
                                                   const float* __restrict__ wih_b,
                                                   const float* __restrict__ b_b,
                                                   const float* __restrict__ wout,
                                                   const float* __restrict__ b_out,
                                                   const float* __restrict__ hf,
                                                   float* __restrict__ out) {
    __shared__ float xs[EDIM];
    __shared__ float red[4];
    int b = blockIdx.x, tid = threadIdx.x;
    if (tid < EDIM) {
        int v = seq[(S_LEN - 1) * NBATCH + b];
        xs[tid] = (v == 0) ? 0.0f : emb[(size_t)v * EDIM + tid];
    }
    __syncthreads();

    int j = tid;  // 0..255 = hidden unit
    float si = b_b[j], sg = b_b[2 * HDIM + j], so = b_b[3 * HDIM + j];
    const float* wi = wih_b + (size_t)j * EDIM;
    const float* wg = wih_b + (size_t)(2 * HDIM + j) * EDIM;
    const float* wo = wih_b + (size_t)(3 * HDIM + j) * EDIM;
#pragma unroll 8
    for (int k = 0; k < EDIM; k += 4) {
        float4v x4 = *(const float4v*)&xs[k];
        float4v a = *(const float4v*)(wi + k);
        float4v c = *(const float4v*)(wg + k);
        float4v d = *(const float4v*)(wo + k);
#pragma unroll
        for (int e = 0; e < 4; ++e) {
            si += a[e] * x4[e];
            sg += c[e] * x4[e];
            so += d[e] * x4[e];
        }
    }
    float cc = sigm(si) * tanh_(sg);   // c = i*g   (f*c0 = 0)
    float hb = sigm(so) * tanh_(cc);   // h = o*tanh(c)
    float partial = hf[(size_t)b * HDIM + j] * wout[j] + hb * wout[HDIM + j];

    float val = partial;
#pragma unroll
    for (int off = 32; off > 0; off >>= 1) val += __shfl_down(val, off, 64);
    int lane = tid & 63, wv = tid >> 6;
    if (lane == 0) red[wv] = val;
    __syncthreads();
    if (tid == 0) out[b] = sigm(red[0] + red[1] + red[2] + red[3] + b_out[0]);
}

extern "C" void kernel_launch(void* const* d_in, const int* in_sizes, int n_in,
                              void* d_out, int out_size, void* d_ws, size_t ws_size,
                              hipStream_t stream) {
    const int* seq = (const int*)d_in[0];
    const float* emb = (const float*)d_in[1];
    const float* Wih_f = (const float*)d_in[2];
    const float* Whh_f = (const float*)d_in[3];
    const float* b_f = (const float*)d_in[4];
    const float* Wih_b = (const float*)d_in[5];
    // d_in[6] = W_hh_b: provably unused (backward scan's only needed output is its
    // step 0, where h0 = 0 so the recurrent term vanishes).
    const float* b_b = (const float*)d_in[7];
    const float* Wout = (const float*)d_in[8];
    const float* b_out = (const float*)d_in[9];
    float* out = (float*)d_out;
    char* ws = (char*)d_ws;

    // 1) weight fragments: W_hh -> fp8 A-frags; W_ih -> bf16 frags
    prep_whh_fp8<<<dim3(128), 256, 0, stream>>>(Whh_f, ws + OFF_WHH8);
    prep_frags<<<dim3(64), 256, 0, stream>>>(Wih_f, ws + OFF_WIH, EDIM, 4, 64 * 4);
    // 2) forward input projections for all timesteps (xg bf16 [t][b][1024])
    input_proj<<<dim3(S_LEN / 4, 4), 256, 0, stream>>>(seq, emb, ws + OFF_WIH, b_f, ws + OFF_XG);
    // 3) sequential forward scan (16 batch groups of 4, 1 CU each, 16 waves)
    lstm_scan<<<dim3(16), 1024, 0, stream>>>(ws + OFF_WHH8, ws + OFF_XG, (float*)(ws + OFF_HF));
    // 4) backward single cell + output projection
    tail_kernel<<<dim3(NBATCH), 256, 0, stream>>>(seq, emb, Wih_b, b_b, Wout, b_out,
                                                  (const float*)(ws + OFF_HF), out);
}

// Round 7
// 696.040 us; speedup vs baseline: 1.4707x; 1.4707x over previous
//
#include <hip/hip_runtime.h>
#include <hip/hip_bf16.h>
#include <stdint.h>
#include <string.h>

// Problem constants
#define S_LEN 512
#define NBATCH 64
#define EDIM 128
#define HDIM 256
#define GDIM 1024  // 4*H

// int8 quantization for the scan GEMM (exact integer MFMA, no fp8 quirks):
//   W_q = rint(W*1024) (|W|<=1/16 -> |W_q|<=64), h_q = rint(h*127),
//   gates = acc_i32 / (127*1024) + xg.
#define WQ_SCALE 1024.0f
#define HQ_SCALE 127.0f
#define DEQ_SCALE (1.0f / 130048.0f)  // 1/(127*1024)

typedef __attribute__((ext_vector_type(8))) short short8;   // 8 bf16 (4 VGPRs) MFMA frag
typedef __attribute__((ext_vector_type(4))) short short4v;  // 4 bf16
typedef __attribute__((ext_vector_type(4))) float float4v;  // MFMA acc
typedef __attribute__((ext_vector_type(4))) int int4v;      // 16B i8 operand / i32 acc

// Workspace layout (bytes)
#define OFF_WHH8 0u
#define SZ_WHH8 (256u * 64u * 16u)           // 256 KB: W_hh_f i8 A-frags (K=64 layout)
#define OFF_WIH (OFF_WHH8 + SZ_WHH8)
#define SZ_WIH (64u * 4u * 64u * 16u)        // 256 KB: W_ih_f bf16 frags
#define OFF_XG ((size_t)(OFF_WIH + SZ_WIH))
#define SZ_XG ((size_t)S_LEN * NBATCH * GDIM * 2)  // 67 MB: xg bf16 [t][b][1024]
#define OFF_HF (OFF_XG + SZ_XG)              // 64 KB: h_f final, fp32 [64][256]

__device__ __forceinline__ short f2bf(float f) {
    union { float f; unsigned u; } v;
    v.f = f;
    unsigned r = (v.u + 0x7fffu + ((v.u >> 16) & 1u)) >> 16;  // RNE
    return (short)r;
}
__device__ __forceinline__ float bf2f(short s) {
    union { unsigned u; float f; } v;
    v.u = ((unsigned)(unsigned short)s) << 16;
    return v.f;
}
__device__ __forceinline__ float sigm(float x) {
    float e = __expf(-x);                    // v_exp
    return __builtin_amdgcn_rcpf(1.0f + e);  // v_rcp
}
__device__ __forceinline__ float tanh_(float x) {
    float e = __expf(2.0f * x);              // overflow -> inf -> rcp 0 -> +1; underflow -> -1
    return 1.0f - 2.0f * __builtin_amdgcn_rcpf(e + 1.0f);
}

// ---------------------------------------------------------------------------
// Prep A: fp32 W_ih [G,128] -> bf16 MFMA A-fragments (lane(ln,q) holds
// W[tile*16+ln][c*32+q*8+j], j=0..7).
// ---------------------------------------------------------------------------
__global__ __launch_bounds__(256) void prep_frags(const float* __restrict__ src,
                                                  char* __restrict__ dst,
                                                  int K, int nchunks, int nfrags) {
    int id = blockIdx.x * blockDim.x + threadIdx.x;
    int lane = id & 63;
    int f = id >> 6;
    if (f >= nfrags) return;
    int tile = f / nchunks;
    int c = f - tile * nchunks;
    int row = tile * 16 + (lane & 15);
    int k0 = c * 32 + ((lane >> 4) * 8);
    const float* s = src + (size_t)row * K + k0;
    short8 pack;
#pragma unroll
    for (int j = 0; j < 8; ++j) pack[j] = f2bf(s[j]);
    *(short8*)(dst + ((size_t)f * 64 + lane) * 16) = pack;
}

// ---------------------------------------------------------------------------
// Prep B: fp32 W_hh [1024,256] -> int8 A-fragments for mfma_i32_16x16x64_i8,
// scaled by 1024 (|W|<=1/16 -> |W_q|<=64, no clamp needed).
// Fragment f = tile*4 + kc; lane(ln,q) byte b = W[tile*16+ln][kc*64+q*16+b]*1024.
// h B-frags use the SAME (q,byte)->k map (non-scaled family, symmetric like
// the v4-verified fp8 16x16x32).
// ---------------------------------------------------------------------------
__global__ __launch_bounds__(256) void prep_whh_i8(const float* __restrict__ src,
                                                   char* __restrict__ dst) {
    int id = blockIdx.x * blockDim.x + threadIdx.x;  // 256 frags x 64 lanes = 16384
    int lane = id & 63;
    int f = id >> 6;  // tile*4 + kc, f < 256
    int tile = f >> 2, kc = f & 3;
    int row = tile * 16 + (lane & 15);
    int k0 = kc * 64 + ((lane >> 4) * 16);
    const float* s = src + (size_t)row * HDIM + k0;
    union { char b[16]; int4v v; } u;
#pragma unroll
    for (int b = 0; b < 16; ++b)
        u.b[b] = (char)(int)rintf(s[b] * WQ_SCALE);
    *(int4v*)(dst + ((size_t)f * 64 + lane) * 16) = u.v;
}

// ---------------------------------------------------------------------------
// Input projection (transposed): xg[t][b][j] = x[t,b,:] @ W_ih^T + b_f (bf16).
// A = W_ih frag, B = x^T frag -> C[m=j][n=batch].  (unchanged from v4)
// ---------------------------------------------------------------------------
__global__ __launch_bounds__(256) void input_proj(const int* __restrict__ seq,
                                                  const float* __restrict__ emb,
                                                  const char* __restrict__ wih_frags,
                                                  const float* __restrict__ bias,
                                                  char* __restrict__ xg) {
    __shared__ __align__(16) short lx[4][16][136];  // bf16 x-tiles, +8 pad
    int tid = threadIdx.x;
    int t0 = blockIdx.x * 4;
    int g = blockIdx.y;

    // stage x: 64 rows (4 t x 16 batch), 4 threads/row, 32 elems each
    {
        int row = tid >> 2;
        int tt = row >> 4, m = row & 15;
        int k0 = (tid & 3) * 32;
        int v = seq[(t0 + tt) * NBATCH + g * 16 + m];
        const float* src = emb + (size_t)v * EDIM + k0;
        bool zero = (v == 0);
#pragma unroll
        for (int u = 0; u < 32; u += 4) {
            float4v f = *(const float4v*)(src + u);
            short4v p;
#pragma unroll
            for (int e = 0; e < 4; ++e) p[e] = zero ? (short)0 : f2bf(f[e]);
            *(short4v*)&lx[tt][m][k0 + u] = p;
        }
    }
    __syncthreads();

    int lane = tid & 63, w = tid >> 6;
    int ln = lane & 15, q = lane >> 4;

    short8 Bx[4][4];  // x^T B-frags [t][kchunk]
#pragma unroll
    for (int tt = 0; tt < 4; ++tt)
#pragma unroll
        for (int c = 0; c < 4; ++c)
            Bx[tt][c] = *(const short8*)&lx[tt][ln][c * 32 + q * 8];

    for (int nt = 0; nt < 16; ++nt) {
        int tile = w * 16 + nt;
        short8 Aw[4];
#pragma unroll
        for (int c = 0; c < 4; ++c)
            Aw[c] = *(const short8*)(wih_frags + (((size_t)tile * 4 + c) * 64 + lane) * 16);
        float4v b4 = *(const float4v*)(bias + tile * 16 + q * 4);
#pragma unroll
        for (int tt = 0; tt < 4; ++tt) {
            float4v acc = b4;
#pragma unroll
            for (int c = 0; c < 4; ++c)
                acc = __builtin_amdgcn_mfma_f32_16x16x32_bf16(Aw[c], Bx[tt][c], acc, 0, 0, 0);
            short4v p;
#pragma unroll
            for (int r = 0; r < 4; ++r) p[r] = f2bf(acc[r]);
            size_t off = ((size_t)(t0 + tt) * NBATCH + g * 16 + ln) * GDIM + tile * 16 + q * 4;
            *(short4v*)(xg + off * 2) = p;
        }
    }
}

// ---------------------------------------------------------------------------
// Forward LSTM scan, v7 (int8 K=64).
//   Structure identical to v4 (16 blocks x 4 batches, lane-dense activations,
//   register-resident W, one barrier/step). Deltas vs v4:
//   - GEMM: mfma_i32_16x16x64_i8, 16 instr/wave (was 32 fp8 K=32) -> MFMA
//     phase ~1310 cyc/SIMD (was ~2020 measured).
//   - acc zero-init (i32) instead of bf16 xg unpack; xg added at dequant.
//   - h stored as i8 (h*127) in LDS; B-frag = 4x ds_read_b128 (16B contig).
//   - xg prefetch: 4 x 2B scalar loads (lane's own (b,j) per gate).
// ---------------------------------------------------------------------------
__global__ __launch_bounds__(1024, 4) void lstm_scan(const char* __restrict__ whh8,
                                                     const char* __restrict__ xg,
                                                     float* __restrict__ hf_out) {
    __shared__ __align__(16) char hls[2][16][272];   // h_q i8 [buf][batch][H], +16 pad
    __shared__ __align__(16) int scr[16][16 * 20];   // per-wave redistribution scratch
    int tid = threadIdx.x;
    int lane = tid & 63, w = tid >> 6;     // w = 0..15: hidden j-tile
    int ln = lane & 15, q = lane >> 4;
    int bg = blockIdx.x;                    // 16 batch groups of 4

    // W_hh i8 A-frags -> registers (gate tiles i,f,g,o at j-tile w): 64 regs
    int4v Wfr[4][4];
#pragma unroll
    for (int blk = 0; blk < 4; ++blk) {
        int tile = 16 * blk + w;
#pragma unroll
        for (int kc = 0; kc < 4; ++kc)
            Wfr[blk][kc] = *(const int4v*)(whh8 + (((size_t)(tile * 4 + kc)) * 64 + lane) * 16);
    }

    // zero both h buffers (rows 4..15 stay zero forever -> garbage cols bounded)
    {
        int* hp = (int*)&hls[0][0][0];
        for (int i = tid; i < (2 * 16 * 272) / 4; i += 1024) hp[i] = 0;
    }

    const char* hrd = &hls[0][0][0];
    char* hwr = &hls[1][0][0];
    int hoff_rd = ln * 272 + q * 16;         // B-frag: 16 contiguous bytes, +kc*64

    // element-phase ownership: lane (q, rr, b) owns (batch b, j = w*16+q*4+rr)
    int b = ln & 3;
    int rr = ln >> 2;
    int j = w * 16 + q * 4 + rr;
    int hoff_wr = b * 272 + j;               // 1 i8 byte
    int* swr = &scr[w][0] + (q * 4 + ln) * 20;            // source write (valid ln<4)
    const int* srd = &scr[w][0] + (q * 4 + b) * 20 + rr;  // gather: +gate*4

    float cst = 0.0f;

    // xg: lane's own (batch, j); gate g at +g*256 elements = +512 bytes
    const char* xgp = xg + (((size_t)(bg * 4 + b) * GDIM + j) * 2);
    const size_t tstep = (size_t)NBATCH * GDIM * 2;  // 131072 B

    unsigned short xq[4];
#pragma unroll
    for (int blk = 0; blk < 4; ++blk)
        xq[blk] = *(const unsigned short*)(xgp + blk * 512);

    __syncthreads();

    for (int t = 0; t < S_LEN; ++t) {
        // h(t-1) B-frags from read buffer: 4 x ds_read_b128
        int4v Bh[4];
#pragma unroll
        for (int kc = 0; kc < 4; ++kc)
            Bh[kc] = *(const int4v*)(hrd + hoff_rd + kc * 64);

        // stash prefetched xg, then issue next step's prefetch
        float xgf[4];
#pragma unroll
        for (int blk = 0; blk < 4; ++blk) xgf[blk] = bf2f((short)xq[blk]);
        xgp += tstep;
        if (t != S_LEN - 1) {
#pragma unroll
            for (int blk = 0; blk < 4; ++blk)
                xq[blk] = *(const unsigned short*)(xgp + blk * 512);
        }

        // 4 independent i8 MFMA chains, chunk-major, zero-init i32 acc
        int4v a[4];
#pragma unroll
        for (int blk = 0; blk < 4; ++blk) a[blk] = (int4v){0, 0, 0, 0};
#pragma unroll
        for (int kc = 0; kc < 4; ++kc)
#pragma unroll
            for (int blk = 0; blk < 4; ++blk)
                a[blk] = __builtin_amdgcn_mfma_i32_16x16x64_i8(Wfr[blk][kc], Bh[kc], a[blk], 0, 0, 0);

        // same-wave scratch redistribution: source lanes (ln<4) publish 16 gates
        if (ln < 4) {
#pragma unroll
            for (int blk = 0; blk < 4; ++blk)
                *(int4v*)(swr + blk * 4) = a[blk];
        }
        // gather one element's i,f,g,o and dequant+combine with xg
        float gi = fmaf((float)srd[0], DEQ_SCALE, xgf[0]);
        float gf = fmaf((float)srd[4], DEQ_SCALE, xgf[1]);
        float gg = fmaf((float)srd[8], DEQ_SCALE, xgf[2]);
        float go = fmaf((float)srd[12], DEQ_SCALE, xgf[3]);

        // activations + cell update (one element per lane)
        float iv = sigm(gi);
        float fv = sigm(gf);
        float gv = tanh_(gg);
        float ov = sigm(go);
        float cv = fv * cst + iv * gv;
        cst = cv;
        float hv = ov * tanh_(cv);

        // h_q = rint(h*127) -> i8 byte into other buffer
        int hq = (int)rintf(hv * HQ_SCALE);
        hwr[hoff_wr] = (char)hq;

        if (t == S_LEN - 1)
            hf_out[((size_t)(bg * 4 + b)) * HDIM + j] = hv;

        const char* tr = hrd; hrd = hwr; hwr = (char*)tr;
        __syncthreads();
    }
}

// ---------------------------------------------------------------------------
// Tail: backward cell at position S-1 (h0=c0=0 => W_hh_b unused) + output proj.
// One block per batch element; thread j handles hidden unit j.
// ---------------------------------------------------------------------------
__global__ __launch_bounds__(256) void tail_kernel(const int* __restrict__ seq,
                                                   const float* __restrict__ emb,
                                                   const float* __restrict__ wih_b,
                                                   const float* __restrict__ b_b,
                                                   const float* __restrict__ wout,
                                                   const float* __restrict__ b_out,
                                                   const float* __restrict__ hf,
                                                   float* __restrict__ out) {
    __shared__ float xs[EDIM];
    __shared__ float red[4];
    int b = blockIdx.x, tid = threadIdx.x;
    if (tid < EDIM) {
        int v = seq[(S_LEN - 1) * NBATCH + b];
        xs[tid] = (v == 0) ? 0.0f : emb[(size_t)v * EDIM + tid];
    }
    __syncthreads();

    int j = tid;  // 0..255 = hidden unit
    float si = b_b[j], sg = b_b[2 * HDIM + j], so = b_b[3 * HDIM + j];
    const float* wi = wih_b + (size_t)j * EDIM;
    const float* wg = wih_b + (size_t)(2 * HDIM + j) * EDIM;
    const float* wo = wih_b + (size_t)(3 * HDIM + j) * EDIM;
#pragma unroll 8
    for (int k = 0; k < EDIM; k += 4) {
        float4v x4 = *(const float4v*)&xs[k];
        float4v a = *(const float4v*)(wi + k);
        float4v c = *(const float4v*)(wg + k);
        float4v d = *(const float4v*)(wo + k);
#pragma unroll
        for (int e = 0; e < 4; ++e) {
            si += a[e] * x4[e];
            sg += c[e] * x4[e];
            so += d[e] * x4[e];
        }
    }
    float cc = sigm(si) * tanh_(sg);   // c = i*g   (f*c0 = 0)
    float hb = sigm(so) * tanh_(cc);   // h = o*tanh(c)
    float partial = hf[(size_t)b * HDIM + j] * wout[j] + hb * wout[HDIM + j];

    float val = partial;
#pragma unroll
    for (int off = 32; off > 0; off >>= 1) val += __shfl_down(val, off, 64);
    int lane = tid & 63, wv = tid >> 6;
    if (lane == 0) red[wv] = val;
    __syncthreads();
    if (tid == 0) out[b] = sigm(red[0] + red[1] + red[2] + red[3] + b_out[0]);
}

extern "C" void kernel_launch(void* const* d_in, const int* in_sizes, int n_in,
                              void* d_out, int out_size, void* d_ws, size_t ws_size,
                              hipStream_t stream) {
    const int* seq = (const int*)d_in[0];
    const float* emb = (const float*)d_in[1];
    const float* Wih_f = (const float*)d_in[2];
    const float* Whh_f = (const float*)d_in[3];
    const float* b_f = (const float*)d_in[4];
    const float* Wih_b = (const float*)d_in[5];
    // d_in[6] = W_hh_b: provably unused (backward scan's only needed output is its
    // step 0, where h0 = 0 so the recurrent term vanishes).
    const float* b_b = (const float*)d_in[7];
    const float* Wout = (const float*)d_in[8];
    const float* b_out = (const float*)d_in[9];
    float* out = (float*)d_out;
    char* ws = (char*)d_ws;

    // 1) weight fragments: W_hh -> i8 K=64 A-frags (x1024); W_ih -> bf16 frags
    prep_whh_i8<<<dim3(64), 256, 0, stream>>>(Whh_f, ws + OFF_WHH8);
    prep_frags<<<dim3(64), 256, 0, stream>>>(Wih_f, ws + OFF_WIH, EDIM, 4, 64 * 4);
    // 2) forward input projections for all timesteps (xg bf16 [t][b][1024])
    input_proj<<<dim3(S_LEN / 4, 4), 256, 0, stream>>>(seq, emb, ws + OFF_WIH, b_f, ws + OFF_XG);
    // 3) sequential forward scan (16 batch groups of 4, 1 CU each, 16 waves)
    lstm_scan<<<dim3(16), 1024, 0, stream>>>(ws + OFF_WHH8, ws + OFF_XG, (float*)(ws + OFF_HF));
    // 4) backward single cell + output projection
    tail_kernel<<<dim3(NBATCH), 256, 0, stream>>>(seq, emb, Wih_b, b_b, Wout, b_out,
                                                  (const float*)(ws + OFF_HF), out);
}